// Round 7
// baseline (177.992 us; speedup 1.0000x reference)
//
#include <hip/hip_runtime.h>
#include <hip/hip_bf16.h>
#include <math.h>

#define NROW 4096
#define DIM  1024

typedef short v8s __attribute__((ext_vector_type(8)));
typedef float v4f __attribute__((ext_vector_type(4)));

#define GLD16(src, dst) __builtin_amdgcn_global_load_lds( \
    (const __attribute__((address_space(1))) void*)(src), \
    (__attribute__((address_space(3))) void*)(dst), 16, 0, 0)

__device__ __forceinline__ ushort f2bf(float f) {
    __hip_bfloat16 h = __float2bfloat16(f);
    union { __hip_bfloat16 h; ushort u; } x; x.h = h; return x.u;
}
__device__ __forceinline__ ushort4 cvt4(float4 a) {
    ushort4 r; r.x = f2bf(a.x); r.y = f2bf(a.y); r.z = f2bf(a.z); r.w = f2bf(a.w);
    return r;
}

// ---------------------------------------------------------------- merged row stats + bf16 shadows
__global__ __launch_bounds__(256) void k_stats(
    const float* vecs, const float* __restrict__ mass,
    const float* __restrict__ hops, const int* __restrict__ alive,
    const int* __restrict__ is_photon, const float* __restrict__ wci,
    const float* __restrict__ wcj, const float* __restrict__ logc,
    const float* __restrict__ logG, const float* __restrict__ bconf,
    const float* W,
    ushort* vsh, int vstr, ushort* wsh, int wstr,
    double* __restrict__ s_i, double* __restrict__ s_j,
    float* __restrict__ rowAtt, float* __restrict__ rowRep,
    float* __restrict__ massF, int* __restrict__ flags,
    float* __restrict__ rownorm)
{
    const int t = threadIdx.x;
    const int wid = t >> 6, lane = t & 63;

    if (blockIdx.x >= NROW / 4) {                  // ---- W convert part
        const int row = (blockIdx.x - NROW / 4) * 4 + wid;
        const float* wr = W + (size_t)row * DIM;
        ushort4 uc[4];
        #pragma unroll
        for (int q = 0; q < 4; ++q)
            uc[q] = cvt4(*(const float4*)&wr[lane * 4 + q * 256]);
        __syncthreads();                           // needed only for in-place mode
        ushort* wb = wsh + (size_t)row * wstr;
        #pragma unroll
        for (int q = 0; q < 4; ++q)
            *(ushort4*)&wb[lane * 4 + q * 256] = uc[q];
        return;
    }

    const int row = blockIdx.x * 4 + wid;
    const float* vr = vecs + (size_t)row * DIM;
    double di = 0.0, dj = 0.0, ss = 0.0;
    ushort4 uc[4];
    #pragma unroll
    for (int q = 0; q < 4; ++q) {
        int base = lane * 4 + q * 256;             // coalesced: 64 lanes x 16B contiguous
        float4 pv = *(const float4*)&vr[base];
        float4 pi = *(const float4*)&wci[base];
        float4 pj = *(const float4*)&wcj[base];
        di += (double)pv.x * pi.x + (double)pv.y * pi.y + (double)pv.z * pi.z + (double)pv.w * pi.w;
        dj += (double)pv.x * pj.x + (double)pv.y * pj.y + (double)pv.z * pj.z + (double)pv.w * pj.w;
        ss += (double)pv.x * pv.x + (double)pv.y * pv.y + (double)pv.z * pv.z + (double)pv.w * pv.w;
        uc[q] = cvt4(pv);
    }
    __syncthreads();   // in-place mode: fp32 reads drained before overwriting
    ushort* vb = vsh + (size_t)row * vstr;
    #pragma unroll
    for (int q = 0; q < 4; ++q)
        *(ushort4*)&vb[lane * 4 + q * 256] = uc[q];
    #pragma unroll
    for (int off = 32; off > 0; off >>= 1) {
        di += __shfl_down(di, off);
        dj += __shfl_down(dj, off);
        ss += __shfl_down(ss, off);
    }
    if (lane == 0) {
        double c  = fmax(exp((double)logc[0]), 1e-6);
        double G  = exp((double)logG[0]);
        double dl = (double)hops[row] / c;
        double lam = (is_photon[row] != 0) ? 1.0 : exp(-dl);
        double rs  = fmax(dl, 0.1);
        double cd  = (dl <= 1.0) ? 1.0 : exp(-dl + 1.0);
        double m   = (double)mass[row];
        s_i[row] = di;
        s_j[row] = dj + (double)bconf[0];                     // b_conf folded here
        rowAtt[row] = (float)(lam * G * m / (rs * rs) * cd);  // * m_j * (0.5+0.5R)
        rowRep[row] = (float)(-lam * m);                      // * conflict * m_j
        massF[row]  = (float)m;
        flags[row]  = ((alive[row] != 0) ? 1 : 0) | ((sqrt(ss) < 1e-8) ? 2 : 0);
        rownorm[row] = 0.0f;                                  // init for k_proj atomics
    }
}

// ---------------------------------------------------------------- v = vecs @ W^T + b
// 64x64 tiles, BK=64, grid (16,64) = 1024 blocks. Proven r1/r2 structure
// (queue 4/CU is already below any residency cap; BK=32 buys nothing here).
__global__ __launch_bounds__(256) void k_proj(
    const ushort* __restrict__ vsh, int vstr,
    const ushort* __restrict__ wsh, int wstr,
    const float* __restrict__ bias, ushort* __restrict__ vout,
    float* __restrict__ rownorm)
{
    __shared__ ushort As[64 * 64], Bs[64 * 64];
    const int t = threadIdx.x;
    const int m0 = blockIdx.y * 64, n0 = blockIdx.x * 64;
    const int wid = t >> 6, lane = t & 63;
    const int wm = wid >> 1, wn = wid & 1;
    const int quad = lane >> 4, l16 = lane & 15;
    const int sr = t >> 3, sc = t & 7;
    v4f acc[2][2];
    #pragma unroll
    for (int i = 0; i < 2; i++)
        #pragma unroll
        for (int j = 0; j < 2; j++) acc[i][j] = (v4f){0.f, 0.f, 0.f, 0.f};

    #pragma unroll
    for (int p = 0; p < 2; ++p) {                  // prologue stage k0=0
        int r = p * 32 + sr;
        int ksw = (sc ^ (r & 7)) * 8;
        GLD16(&vsh[(size_t)(m0 + r) * vstr + ksw], &As[p * 2048 + wid * 512]);
        GLD16(&wsh[(size_t)(n0 + r) * wstr + ksw], &Bs[p * 2048 + wid * 512]);
    }
    __syncthreads();

    for (int k0 = 0; k0 < DIM; k0 += 64) {
        #pragma unroll
        for (int ks = 0; ks < 2; ++ks) {
            v8s af[2], bfr[2];
            #pragma unroll
            for (int mi = 0; mi < 2; mi++) {
                int row = wm * 32 + mi * 16 + l16;
                af[mi] = *(const v8s*)&As[row * 64 + (((ks * 4 + quad) ^ (l16 & 7)) * 8)];
            }
            #pragma unroll
            for (int ni = 0; ni < 2; ni++) {
                int row = wn * 32 + ni * 16 + l16;
                bfr[ni] = *(const v8s*)&Bs[row * 64 + (((ks * 4 + quad) ^ (l16 & 7)) * 8)];
            }
            #pragma unroll
            for (int mi = 0; mi < 2; mi++)
                #pragma unroll
                for (int ni = 0; ni < 2; ni++)
                    acc[mi][ni] = __builtin_amdgcn_mfma_f32_16x16x32_bf16(af[mi], bfr[ni], acc[mi][ni], 0, 0, 0);
        }
        if (k0 + 64 < DIM) {
            __syncthreads();        // reads drained before restage
            int k1 = k0 + 64;
            #pragma unroll
            for (int p = 0; p < 2; ++p) {
                int r = p * 32 + sr;
                int ksw = (sc ^ (r & 7)) * 8;
                GLD16(&vsh[(size_t)(m0 + r) * vstr + k1 + ksw], &As[p * 2048 + wid * 512]);
                GLD16(&wsh[(size_t)(n0 + r) * wstr + k1 + ksw], &Bs[p * 2048 + wid * 512]);
            }
            __syncthreads();
        }
    }

    float bcol[2];
    #pragma unroll
    for (int ni = 0; ni < 2; ni++) bcol[ni] = bias[n0 + wn * 32 + ni * 16 + l16];
    #pragma unroll
    for (int mi = 0; mi < 2; mi++)
        #pragma unroll
        for (int r = 0; r < 4; r++) {
            int row = m0 + wm * 32 + mi * 16 + quad * 4 + r;
            float ss = 0.0f;
            #pragma unroll
            for (int ni = 0; ni < 2; ni++) {
                int col = n0 + wn * 32 + ni * 16 + l16;
                float vv = acc[mi][ni][r] + bcol[ni];
                vout[(size_t)row * DIM + col] = f2bf(vv);
                ss += vv * vv;
            }
            #pragma unroll
            for (int off = 8; off > 0; off >>= 1) ss += __shfl_down(ss, off);
            if (l16 == 0) atomicAdd(&rownorm[row], ss);
        }
}

// ---------------------------------------------------------------- phi tiles -> FP32 output
// EXACT r2 structure (64^2 triangle, 2080 blocks, 256 thr, 2-barrier loop,
// no XCD swizzle) with ONE change: BK=32 -> LDS 8 KB/block. Rounds 2-6 show
// resident blocks ~= floor(64KB / LDS_per_block) regardless of everything
// else (r2 16KB->3.6, r3 32KB->2.4, r4 24KB->2, r6 16KB->4): testing the
// ~64KB-pool hypothesis. If true, 8 blocks/CU resident -> occupancy ~2x.
// Bank swizzle re-derived for 64B row stride: XOR selector (row>>1)&3
// (row&3 would alias with row-parity bank bit -> 4-way conflict; parity-bit
// form restores the 8 bank-group spread that measured 0 conflicts at BK=64).
__global__ __launch_bounds__(256) void k_phi(
    const ushort* __restrict__ vn,
    const double* __restrict__ s_i, const double* __restrict__ s_j,
    const float* __restrict__ rowAtt, const float* __restrict__ rowRep,
    const float* __restrict__ massF, const int* __restrict__ flags,
    const float* __restrict__ rownorm, float* __restrict__ out)
{
    __shared__ ushort As[64 * 32], Bs[64 * 32];    // 4 KB + 4 KB
    const int t = threadIdx.x;
    const int id = blockIdx.x;
    int r = (int)((sqrtf(8.0f * (float)id + 1.0f) - 1.0f) * 0.5f);
    while ((((r + 1) * (r + 2)) >> 1) <= id) ++r;
    while (((r * (r + 1)) >> 1) > id) --r;
    const int bi = r, bj = id - ((r * (r + 1)) >> 1);   // bi >= bj
    const bool diag = (bi == bj);
    const int m0 = bi * 64, n0 = bj * 64;
    const int wid = t >> 6, lane = t & 63;
    const int wm = wid >> 1, wn = wid & 1;
    const int quad = lane >> 4, l16 = lane & 15;
    const int sr = t >> 2, sc = t & 3;             // staging: 64 rows x 4 chunks
    const double LN4 = 1.3862943611198906;  // sigmoid(x)>0.8  <=>  x>ln4

    // stage one K-tile (32 cols): 1 GLD16/thread per buffer; linear LDS dest
    // &As[t*8] == row sr, chunk sc; global source chunk = sc ^ ((sr>>1)&3).
    auto ISSUE = [&](int k0) {
        int ksw = (sc ^ ((sr >> 1) & 3)) * 8;
        GLD16(&vn[(size_t)(m0 + sr) * DIM + k0 + ksw], &As[t * 8]);
        GLD16(&vn[(size_t)(n0 + sr) * DIM + k0 + ksw], &Bs[t * 8]);
    };
    ISSUE(0);

    // ---- fused light tile (transposed position: rows from bj-tile, cols from
    //      bi-tile; col > row everywhere). Store-only, overlaps staging.
    if (!diag) {
        double csjL[2]; float cmL[2]; int colL[2];
        #pragma unroll
        for (int ni = 0; ni < 2; ni++) {
            int col = m0 + wn * 32 + ni * 16 + l16;
            colL[ni] = col;
            csjL[ni] = s_j[col];
            cmL[ni]  = (flags[col] & 1) ? massF[col] : 0.f;
        }
        #pragma unroll
        for (int mi = 0; mi < 2; mi++)
            #pragma unroll
            for (int rr = 0; rr < 4; rr++) {
                int row = n0 + wm * 32 + mi * 16 + quad * 4 + rr;
                double si = s_i[row];
                float  rRm = (flags[row] & 1) ? rowRep[row] : 0.f;
                size_t ob = (size_t)row * NROW;
                #pragma unroll
                for (int ni = 0; ni < 2; ni++) {
                    double x = si + csjL[ni];
                    float v = 0.f;
                    if (x > LN4) {
                        float e = __expf(-(float)x);
                        v = rRm * cmL[ni] * __builtin_amdgcn_rcpf(1.0f + e);
                    }
                    out[ob + colL[ni]] = v;
                }
            }
    }

    // ---- heavy column stats (overlap with staging latency)
    double csjH[2]; float cmn[2], cc[2]; int colH[2];
    #pragma unroll
    for (int ni = 0; ni < 2; ni++) {
        int col = n0 + wn * 32 + ni * 16 + l16;
        int cf = flags[col];
        float cma = (cf & 1) ? massF[col] : 0.f;
        colH[ni] = col;
        csjH[ni] = s_j[col];
        cmn[ni]  = cma;
        cc[ni]   = (cf & 2) ? 0.f
                 : cma * __builtin_amdgcn_rcpf(fmaxf(sqrtf(rownorm[col]), 1e-8f));
    }

    v4f acc[2][2];
    #pragma unroll
    for (int i = 0; i < 2; i++)
        #pragma unroll
        for (int j = 0; j < 2; j++) acc[i][j] = (v4f){0.f, 0.f, 0.f, 0.f};

    __syncthreads();
    for (int k0 = 0; k0 < DIM; k0 += 32) {
        v8s af[2], bfr[2];
        #pragma unroll
        for (int mi = 0; mi < 2; mi++) {
            int row = wm * 32 + mi * 16 + l16;
            af[mi] = *(const v8s*)&As[row * 32 + ((quad ^ ((l16 >> 1) & 3)) * 8)];
        }
        #pragma unroll
        for (int ni = 0; ni < 2; ni++) {
            int row = wn * 32 + ni * 16 + l16;
            bfr[ni] = *(const v8s*)&Bs[row * 32 + ((quad ^ ((l16 >> 1) & 3)) * 8)];
        }
        #pragma unroll
        for (int mi = 0; mi < 2; mi++)
            #pragma unroll
            for (int ni = 0; ni < 2; ni++)
                acc[mi][ni] = __builtin_amdgcn_mfma_f32_16x16x32_bf16(af[mi], bfr[ni], acc[mi][ni], 0, 0, 0);
        if (k0 + 32 < DIM) {
            __syncthreads();        // reads drained before restage
            ISSUE(k0 + 32);
            __syncthreads();
        }
    }

    // ---- heavy epilogue: 8 rows x 2 cols per thread (math identical to r2)
    #pragma unroll
    for (int mi = 0; mi < 2; mi++)
        #pragma unroll
        for (int rr = 0; rr < 4; rr++) {
            int row = m0 + wm * 32 + mi * 16 + quad * 4 + rr;
            int fi = flags[row];
            float rA  = rowAtt[row];
            float riv = __builtin_amdgcn_rcpf(fmaxf(sqrtf(rownorm[row]), 1e-8f));
            float a1  = (fi & 1) ? 0.5f * rA : 0.f;                 // alive gate folded
            float a2  = ((fi & 3) == 1) ? 0.5f * rA * riv : 0.f;    // + zero-norm gate
            float rRm = (fi & 1) ? rowRep[row] : 0.f;
            double si = s_i[row];
            size_t ob = (size_t)row * NROW;
            #pragma unroll
            for (int ni = 0; ni < 2; ni++) {
                int col = colH[ni];
                double x = si + csjH[ni];
                float  acv = acc[mi][ni][rr];
                float  att = fmaf(a2 * cc[ni], acv, a1 * cmn[ni]);
                float  e   = __expf(-(float)x);
                float  rep = rRm * cmn[ni] * __builtin_amdgcn_rcpf(1.0f + e);
                float  v   = (x > LN4) ? rep : att;
                if (diag) {
                    if (col > row) v = (x > LN4) ? rep : 0.f;   // upper part: rep-only
                    if (col == row) v = 0.f;                    // diagonal zero
                }
                out[ob + col] = v;
            }
        }
}

extern "C" void kernel_launch(void* const* d_in, const int* in_sizes, int n_in,
                              void* d_out, int out_size, void* d_ws, size_t ws_size,
                              hipStream_t stream)
{
    const float* vecs      = (const float*)d_in[0];
    const float* mass      = (const float*)d_in[1];
    const float* hops      = (const float*)d_in[2];
    const int*   alive     = (const int*)d_in[3];
    const int*   is_photon = (const int*)d_in[4];
    const float* W         = (const float*)d_in[5];
    const float* Wb        = (const float*)d_in[6];
    const float* wci       = (const float*)d_in[7];
    const float* wcj       = (const float*)d_in[8];
    const float* bconf     = (const float*)d_in[9];
    const float* logc      = (const float*)d_in[10];
    const float* logG      = (const float*)d_in[11];

    char* ws = (char*)d_ws;
    double* s_i     = (double*)(ws);                 // 32 KB
    double* s_j     = (double*)(ws + 32768);         // 32 KB (holds s_j + b_conf)
    float*  rowAtt  = (float*)(ws + 65536);          // 16 KB
    float*  rowRep  = (float*)(ws + 81920);          // 16 KB
    float*  massF   = (float*)(ws + 98304);          // 16 KB
    int*    flagsA  = (int*)(ws + 114688);           // 16 KB
    float*  rownorm = (float*)(ws + 131072);         // 16 KB
    ushort* vn      = (ushort*)(ws + 147456);        // 8 MB (unnormalized v, bf16)

    // bf16 shadows: dense in d_ws if it fits (d_in stays pristine), else
    // legacy in-place second-half layout.
    const size_t VSH_OFF = 147456 + (size_t)NROW * DIM * 2;       // after vn
    const size_t WSH_OFF = VSH_OFF + (size_t)NROW * DIM * 2;      // after vecs shadow
    const size_t NEED    = WSH_OFF + (size_t)DIM * DIM * 2;
    ushort *vsh, *wsh; int vstr, wstr;
    if (ws_size >= NEED) {
        vsh = (ushort*)(ws + VSH_OFF); vstr = DIM;
        wsh = (ushort*)(ws + WSH_OFF); wstr = DIM;
    } else {
        vsh = (ushort*)vecs + 1024; vstr = 2048;     // in-place (poisons d_in)
        wsh = (ushort*)W + 1024;    wstr = 2048;
    }

    k_stats<<<dim3(NROW / 4 + DIM / 4), dim3(256), 0, stream>>>(
        vecs, mass, hops, alive, is_photon, wci, wcj, logc, logG, bconf, W,
        vsh, vstr, wsh, wstr,
        s_i, s_j, rowAtt, rowRep, massF, flagsA, rownorm);
    k_proj<<<dim3(DIM / 64, NROW / 64), dim3(256), 0, stream>>>(
        vsh, vstr, wsh, wstr, Wb, vn, rownorm);
    k_phi<<<dim3(2080), dim3(256), 0, stream>>>(
        vn, s_i, s_j, rowAtt, rowRep, massF, flagsA, rownorm, (float*)d_out);
}

// Round 8
// 167.786 us; speedup vs baseline: 1.0608x; 1.0608x over previous
//
#include <hip/hip_runtime.h>
#include <hip/hip_bf16.h>
#include <math.h>

#define NROW 4096
#define DIM  1024

typedef short v8s __attribute__((ext_vector_type(8)));
typedef float v4f __attribute__((ext_vector_type(4)));

#define GLD16(src, dst) __builtin_amdgcn_global_load_lds( \
    (const __attribute__((address_space(1))) void*)(src), \
    (__attribute__((address_space(3))) void*)(dst), 16, 0, 0)

__device__ __forceinline__ ushort f2bf(float f) {
    __hip_bfloat16 h = __float2bfloat16(f);
    union { __hip_bfloat16 h; ushort u; } x; x.h = h; return x.u;
}
__device__ __forceinline__ ushort4 cvt4(float4 a) {
    ushort4 r; r.x = f2bf(a.x); r.y = f2bf(a.y); r.z = f2bf(a.z); r.w = f2bf(a.w);
    return r;
}

// ---------------------------------------------------------------- merged row stats + bf16 shadows
__global__ __launch_bounds__(256) void k_stats(
    const float* vecs, const float* __restrict__ mass,
    const float* __restrict__ hops, const int* __restrict__ alive,
    const int* __restrict__ is_photon, const float* __restrict__ wci,
    const float* __restrict__ wcj, const float* __restrict__ logc,
    const float* __restrict__ logG, const float* __restrict__ bconf,
    const float* W,
    ushort* vsh, int vstr, ushort* wsh, int wstr,
    double* __restrict__ s_i, double* __restrict__ s_j,
    float* __restrict__ rowAtt, float* __restrict__ rowRep,
    float* __restrict__ massF, int* __restrict__ flags,
    float* __restrict__ rownorm)
{
    const int t = threadIdx.x;
    const int wid = t >> 6, lane = t & 63;

    if (blockIdx.x >= NROW / 4) {                  // ---- W convert part
        const int row = (blockIdx.x - NROW / 4) * 4 + wid;
        const float* wr = W + (size_t)row * DIM;
        ushort4 uc[4];
        #pragma unroll
        for (int q = 0; q < 4; ++q)
            uc[q] = cvt4(*(const float4*)&wr[lane * 4 + q * 256]);
        __syncthreads();                           // needed only for in-place mode
        ushort* wb = wsh + (size_t)row * wstr;
        #pragma unroll
        for (int q = 0; q < 4; ++q)
            *(ushort4*)&wb[lane * 4 + q * 256] = uc[q];
        return;
    }

    const int row = blockIdx.x * 4 + wid;
    const float* vr = vecs + (size_t)row * DIM;
    double di = 0.0, dj = 0.0, ss = 0.0;
    ushort4 uc[4];
    #pragma unroll
    for (int q = 0; q < 4; ++q) {
        int base = lane * 4 + q * 256;             // coalesced: 64 lanes x 16B contiguous
        float4 pv = *(const float4*)&vr[base];
        float4 pi = *(const float4*)&wci[base];
        float4 pj = *(const float4*)&wcj[base];
        di += (double)pv.x * pi.x + (double)pv.y * pi.y + (double)pv.z * pi.z + (double)pv.w * pi.w;
        dj += (double)pv.x * pj.x + (double)pv.y * pj.y + (double)pv.z * pj.z + (double)pv.w * pj.w;
        ss += (double)pv.x * pv.x + (double)pv.y * pv.y + (double)pv.z * pv.z + (double)pv.w * pv.w;
        uc[q] = cvt4(pv);
    }
    __syncthreads();   // in-place mode: fp32 reads drained before overwriting
    ushort* vb = vsh + (size_t)row * vstr;
    #pragma unroll
    for (int q = 0; q < 4; ++q)
        *(ushort4*)&vb[lane * 4 + q * 256] = uc[q];
    #pragma unroll
    for (int off = 32; off > 0; off >>= 1) {
        di += __shfl_down(di, off);
        dj += __shfl_down(dj, off);
        ss += __shfl_down(ss, off);
    }
    if (lane == 0) {
        double c  = fmax(exp((double)logc[0]), 1e-6);
        double G  = exp((double)logG[0]);
        double dl = (double)hops[row] / c;
        double lam = (is_photon[row] != 0) ? 1.0 : exp(-dl);
        double rs  = fmax(dl, 0.1);
        double cd  = (dl <= 1.0) ? 1.0 : exp(-dl + 1.0);
        double m   = (double)mass[row];
        s_i[row] = di;
        s_j[row] = dj + (double)bconf[0];                     // b_conf folded here
        rowAtt[row] = (float)(lam * G * m / (rs * rs) * cd);  // * m_j * (0.5+0.5R)
        rowRep[row] = (float)(-lam * m);                      // * conflict * m_j
        massF[row]  = (float)m;
        flags[row]  = ((alive[row] != 0) ? 1 : 0) | ((sqrt(ss) < 1e-8) ? 2 : 0);
        rownorm[row] = 0.0f;                                  // init for k_proj atomics
    }
}

// ---------------------------------------------------------------- v = vecs @ W^T + b
// 64x64 tiles, BK=64, grid (16,64) = 1024 blocks. Proven r1/r2 structure.
__global__ __launch_bounds__(256) void k_proj(
    const ushort* __restrict__ vsh, int vstr,
    const ushort* __restrict__ wsh, int wstr,
    const float* __restrict__ bias, ushort* __restrict__ vout,
    float* __restrict__ rownorm)
{
    __shared__ ushort As[64 * 64], Bs[64 * 64];
    const int t = threadIdx.x;
    const int m0 = blockIdx.y * 64, n0 = blockIdx.x * 64;
    const int wid = t >> 6, lane = t & 63;
    const int wm = wid >> 1, wn = wid & 1;
    const int quad = lane >> 4, l16 = lane & 15;
    const int sr = t >> 3, sc = t & 7;
    v4f acc[2][2];
    #pragma unroll
    for (int i = 0; i < 2; i++)
        #pragma unroll
        for (int j = 0; j < 2; j++) acc[i][j] = (v4f){0.f, 0.f, 0.f, 0.f};

    #pragma unroll
    for (int p = 0; p < 2; ++p) {                  // prologue stage k0=0
        int r = p * 32 + sr;
        int ksw = (sc ^ (r & 7)) * 8;
        GLD16(&vsh[(size_t)(m0 + r) * vstr + ksw], &As[p * 2048 + wid * 512]);
        GLD16(&wsh[(size_t)(n0 + r) * wstr + ksw], &Bs[p * 2048 + wid * 512]);
    }
    __syncthreads();

    for (int k0 = 0; k0 < DIM; k0 += 64) {
        #pragma unroll
        for (int ks = 0; ks < 2; ++ks) {
            v8s af[2], bfr[2];
            #pragma unroll
            for (int mi = 0; mi < 2; mi++) {
                int row = wm * 32 + mi * 16 + l16;
                af[mi] = *(const v8s*)&As[row * 64 + (((ks * 4 + quad) ^ (l16 & 7)) * 8)];
            }
            #pragma unroll
            for (int ni = 0; ni < 2; ni++) {
                int row = wn * 32 + ni * 16 + l16;
                bfr[ni] = *(const v8s*)&Bs[row * 64 + (((ks * 4 + quad) ^ (l16 & 7)) * 8)];
            }
            #pragma unroll
            for (int mi = 0; mi < 2; mi++)
                #pragma unroll
                for (int ni = 0; ni < 2; ni++)
                    acc[mi][ni] = __builtin_amdgcn_mfma_f32_16x16x32_bf16(af[mi], bfr[ni], acc[mi][ni], 0, 0, 0);
        }
        if (k0 + 64 < DIM) {
            __syncthreads();        // reads drained before restage
            int k1 = k0 + 64;
            #pragma unroll
            for (int p = 0; p < 2; ++p) {
                int r = p * 32 + sr;
                int ksw = (sc ^ (r & 7)) * 8;
                GLD16(&vsh[(size_t)(m0 + r) * vstr + k1 + ksw], &As[p * 2048 + wid * 512]);
                GLD16(&wsh[(size_t)(n0 + r) * wstr + k1 + ksw], &Bs[p * 2048 + wid * 512]);
            }
            __syncthreads();
        }
    }

    float bcol[2];
    #pragma unroll
    for (int ni = 0; ni < 2; ni++) bcol[ni] = bias[n0 + wn * 32 + ni * 16 + l16];
    #pragma unroll
    for (int mi = 0; mi < 2; mi++)
        #pragma unroll
        for (int r = 0; r < 4; r++) {
            int row = m0 + wm * 32 + mi * 16 + quad * 4 + r;
            float ss = 0.0f;
            #pragma unroll
            for (int ni = 0; ni < 2; ni++) {
                int col = n0 + wn * 32 + ni * 16 + l16;
                float vv = acc[mi][ni][r] + bcol[ni];
                vout[(size_t)row * DIM + col] = f2bf(vv);
                ss += vv * vv;
            }
            #pragma unroll
            for (int off = 8; off > 0; off >>= 1) ss += __shfl_down(ss, off);
            if (l16 == 0) atomicAdd(&rownorm[row], ss);
        }
}

// ---------------------------------------------------------------- phi tiles -> FP32 output
// BIT-EXACT round-2 k_phi (measured best: 52.6 us, 45% occ, 0 conflicts)
// plus ONE line: bijective XCD-chunked block-id remap (2080 = 8*260).
// r6 measured this mechanism at identical grid: FETCH 76 -> 31 MB. r2 ran at
// 2.78 TB/s (partially BW-coupled), so the traffic cut should convert to time.
__global__ __launch_bounds__(256, 5) void k_phi(
    const ushort* __restrict__ vn,
    const double* __restrict__ s_i, const double* __restrict__ s_j,
    const float* __restrict__ rowAtt, const float* __restrict__ rowRep,
    const float* __restrict__ massF, const int* __restrict__ flags,
    const float* __restrict__ rownorm, float* __restrict__ out)
{
    __shared__ ushort As[64 * 64], Bs[64 * 64];
    const int t = threadIdx.x;
    const int raw = blockIdx.x;
    const int id = (raw & 7) * 260 + (raw >> 3);        // XCD-chunked, bijective
    int r = (int)((sqrtf(8.0f * (float)id + 1.0f) - 1.0f) * 0.5f);
    while ((((r + 1) * (r + 2)) >> 1) <= id) ++r;
    while (((r * (r + 1)) >> 1) > id) --r;
    const int bi = r, bj = id - ((r * (r + 1)) >> 1);   // bi >= bj
    const bool diag = (bi == bj);
    const int m0 = bi * 64, n0 = bj * 64;
    const int wid = t >> 6, lane = t & 63;
    const int wm = wid >> 1, wn = wid & 1;
    const int quad = lane >> 4, l16 = lane & 15;
    const int sr = t >> 3, sc = t & 7;
    const double LN4 = 1.3862943611198906;  // sigmoid(x)>0.8  <=>  x>ln4

    // ---- issue first K-tile staging immediately (light tile overlaps it)
    #pragma unroll
    for (int p = 0; p < 2; ++p) {
        int rr = p * 32 + sr;
        int ksw = (sc ^ (rr & 7)) * 8;
        GLD16(&vn[(size_t)(m0 + rr) * DIM + ksw], &As[p * 2048 + wid * 512]);
        GLD16(&vn[(size_t)(n0 + rr) * DIM + ksw], &Bs[p * 2048 + wid * 512]);
    }

    // ---- fused light tile (transposed position: rows from bj-tile, cols from
    //      bi-tile; col > row everywhere). Store-only, overlaps loads above.
    if (!diag) {
        double csjL[2]; float cmL[2]; int colL[2];
        #pragma unroll
        for (int ni = 0; ni < 2; ni++) {
            int col = m0 + wn * 32 + ni * 16 + l16;
            colL[ni] = col;
            csjL[ni] = s_j[col];
            cmL[ni]  = (flags[col] & 1) ? massF[col] : 0.f;
        }
        #pragma unroll
        for (int mi = 0; mi < 2; mi++)
            #pragma unroll
            for (int rr = 0; rr < 4; rr++) {
                int row = n0 + wm * 32 + mi * 16 + quad * 4 + rr;
                double si = s_i[row];
                float  rRm = (flags[row] & 1) ? rowRep[row] : 0.f;
                size_t ob = (size_t)row * NROW;
                #pragma unroll
                for (int ni = 0; ni < 2; ni++) {
                    double x = si + csjL[ni];
                    float v = 0.f;
                    if (x > LN4) {
                        float e = __expf(-(float)x);
                        v = rRm * cmL[ni] * __builtin_amdgcn_rcpf(1.0f + e);
                    }
                    out[ob + colL[ni]] = v;
                }
            }
    }

    // ---- heavy column stats (load early, overlap with staging latency)
    double csjH[2]; float cmn[2], cc[2]; int colH[2];
    #pragma unroll
    for (int ni = 0; ni < 2; ni++) {
        int col = n0 + wn * 32 + ni * 16 + l16;
        int cf = flags[col];
        float cma = (cf & 1) ? massF[col] : 0.f;
        colH[ni] = col;
        csjH[ni] = s_j[col];
        cmn[ni]  = cma;
        cc[ni]   = (cf & 2) ? 0.f
                 : cma * __builtin_amdgcn_rcpf(fmaxf(sqrtf(rownorm[col]), 1e-8f));
    }

    v4f acc[2][2];
    #pragma unroll
    for (int i = 0; i < 2; i++)
        #pragma unroll
        for (int j = 0; j < 2; j++) acc[i][j] = (v4f){0.f, 0.f, 0.f, 0.f};

    __syncthreads();
    for (int k0 = 0; k0 < DIM; k0 += 64) {
        #pragma unroll
        for (int ks = 0; ks < 2; ++ks) {
            v8s af[2], bfr[2];
            #pragma unroll
            for (int mi = 0; mi < 2; mi++) {
                int row = wm * 32 + mi * 16 + l16;
                af[mi] = *(const v8s*)&As[row * 64 + (((ks * 4 + quad) ^ (l16 & 7)) * 8)];
            }
            #pragma unroll
            for (int ni = 0; ni < 2; ni++) {
                int row = wn * 32 + ni * 16 + l16;
                bfr[ni] = *(const v8s*)&Bs[row * 64 + (((ks * 4 + quad) ^ (l16 & 7)) * 8)];
            }
            #pragma unroll
            for (int mi = 0; mi < 2; mi++)
                #pragma unroll
                for (int ni = 0; ni < 2; ni++)
                    acc[mi][ni] = __builtin_amdgcn_mfma_f32_16x16x32_bf16(af[mi], bfr[ni], acc[mi][ni], 0, 0, 0);
        }
        if (k0 + 64 < DIM) {
            __syncthreads();          // reads drained before restage
            int k1 = k0 + 64;
            #pragma unroll
            for (int p = 0; p < 2; ++p) {
                int rr = p * 32 + sr;
                int ksw = (sc ^ (rr & 7)) * 8;
                GLD16(&vn[(size_t)(m0 + rr) * DIM + k1 + ksw], &As[p * 2048 + wid * 512]);
                GLD16(&vn[(size_t)(n0 + rr) * DIM + k1 + ksw], &Bs[p * 2048 + wid * 512]);
            }
            __syncthreads();
        }
    }

    // ---- heavy epilogue: 8 rows x 2 cols per thread
    #pragma unroll
    for (int mi = 0; mi < 2; mi++)
        #pragma unroll
        for (int rr = 0; rr < 4; rr++) {
            int row = m0 + wm * 32 + mi * 16 + quad * 4 + rr;
            int fi = flags[row];
            float rA  = rowAtt[row];
            float riv = __builtin_amdgcn_rcpf(fmaxf(sqrtf(rownorm[row]), 1e-8f));
            float a1  = (fi & 1) ? 0.5f * rA : 0.f;                 // alive gate folded
            float a2  = ((fi & 3) == 1) ? 0.5f * rA * riv : 0.f;    // + zero-norm gate
            float rRm = (fi & 1) ? rowRep[row] : 0.f;
            double si = s_i[row];
            size_t ob = (size_t)row * NROW;
            #pragma unroll
            for (int ni = 0; ni < 2; ni++) {
                double x = si + csjH[ni];
                float  acv = acc[mi][ni][rr];
                float  att = fmaf(a2 * cc[ni], acv, a1 * cmn[ni]);
                float  e   = __expf(-(float)x);
                float  rep = rRm * cmn[ni] * __builtin_amdgcn_rcpf(1.0f + e);
                float  v   = (x > LN4) ? rep : att;
                if (diag) {
                    int col = colH[ni];
                    if (col > row) v = (x > LN4) ? rep : 0.f;   // upper half: rep-only
                    if (col == row) v = 0.f;                    // diagonal zero
                }
                out[ob + colH[ni]] = v;
            }
        }
}

extern "C" void kernel_launch(void* const* d_in, const int* in_sizes, int n_in,
                              void* d_out, int out_size, void* d_ws, size_t ws_size,
                              hipStream_t stream)
{
    const float* vecs      = (const float*)d_in[0];
    const float* mass      = (const float*)d_in[1];
    const float* hops      = (const float*)d_in[2];
    const int*   alive     = (const int*)d_in[3];
    const int*   is_photon = (const int*)d_in[4];
    const float* W         = (const float*)d_in[5];
    const float* Wb        = (const float*)d_in[6];
    const float* wci       = (const float*)d_in[7];
    const float* wcj       = (const float*)d_in[8];
    const float* bconf     = (const float*)d_in[9];
    const float* logc      = (const float*)d_in[10];
    const float* logG      = (const float*)d_in[11];

    char* ws = (char*)d_ws;
    double* s_i     = (double*)(ws);                 // 32 KB
    double* s_j     = (double*)(ws + 32768);         // 32 KB (holds s_j + b_conf)
    float*  rowAtt  = (float*)(ws + 65536);          // 16 KB
    float*  rowRep  = (float*)(ws + 81920);          // 16 KB
    float*  massF   = (float*)(ws + 98304);          // 16 KB
    int*    flagsA  = (int*)(ws + 114688);           // 16 KB
    float*  rownorm = (float*)(ws + 131072);         // 16 KB
    ushort* vn      = (ushort*)(ws + 147456);        // 8 MB (unnormalized v, bf16)

    // bf16 shadows: dense in d_ws if it fits (d_in stays pristine), else
    // legacy in-place second-half layout.
    const size_t VSH_OFF = 147456 + (size_t)NROW * DIM * 2;       // after vn
    const size_t WSH_OFF = VSH_OFF + (size_t)NROW * DIM * 2;      // after vecs shadow
    const size_t NEED    = WSH_OFF + (size_t)DIM * DIM * 2;
    ushort *vsh, *wsh; int vstr, wstr;
    if (ws_size >= NEED) {
        vsh = (ushort*)(ws + VSH_OFF); vstr = DIM;
        wsh = (ushort*)(ws + WSH_OFF); wstr = DIM;
    } else {
        vsh = (ushort*)vecs + 1024; vstr = 2048;     // in-place (poisons d_in)
        wsh = (ushort*)W + 1024;    wstr = 2048;
    }

    k_stats<<<dim3(NROW / 4 + DIM / 4), dim3(256), 0, stream>>>(
        vecs, mass, hops, alive, is_photon, wci, wcj, logc, logG, bconf, W,
        vsh, vstr, wsh, wstr,
        s_i, s_j, rowAtt, rowRep, massF, flagsA, rownorm);
    k_proj<<<dim3(DIM / 64, NROW / 64), dim3(256), 0, stream>>>(
        vsh, vstr, wsh, wstr, Wb, vn, rownorm);
    k_phi<<<dim3(2080), dim3(256), 0, stream>>>(
        vn, s_i, s_j, rowAtt, rowRep, massF, flagsA, rownorm, (float*)d_out);
}